// Round 7
// baseline (251.551 us; speedup 1.0000x reference)
//
#include <hip/hip_runtime.h>

#define D 128
#define SB 256
#define SI 8
#define SCHUNK (SB * SI)

typedef __attribute__((ext_vector_type(8))) short bf16x8;
typedef __attribute__((ext_vector_type(4))) float f32x4;
typedef unsigned int uint32;
typedef unsigned short ushort;

__device__ __forceinline__ ushort bf16rne(float f) {
  uint32 u = __float_as_uint(f);
  uint32 r = u + 0x7FFFu + ((u >> 16) & 1u);
  return (ushort)(r >> 16);
}
__device__ __forceinline__ float bf2f_lo(uint32 h) { return __uint_as_float(h << 16); }
__device__ __forceinline__ float bf2f_hi(uint32 h) { return __uint_as_float(h & 0xFFFF0000u); }
__device__ __forceinline__ uint32 packbf2(float x, float y) {
  return (uint32)bf16rne(x) | ((uint32)bf16rne(y) << 16);
}
__device__ __forceinline__ void acc8(float* a, float w, uint4 h) {
  a[0] += w * bf2f_lo(h.x); a[1] += w * bf2f_hi(h.x);
  a[2] += w * bf2f_lo(h.y); a[3] += w * bf2f_hi(h.y);
  a[4] += w * bf2f_lo(h.z); a[5] += w * bf2f_hi(h.z);
  a[6] += w * bf2f_lo(h.w); a[7] += w * bf2f_hi(h.w);
}
__device__ __forceinline__ void lds_fence() {
  __builtin_amdgcn_sched_barrier(0);
  asm volatile("s_waitcnt lgkmcnt(0)" ::: "memory");
  __builtin_amdgcn_sched_barrier(0);
}

// ---------------- prep: xb convert + degree count + W-conv, one launch -----

__global__ void prep_kernel(const float* __restrict__ x, ushort* __restrict__ xb, int total4,
                            const int* __restrict__ dst, int* __restrict__ cnt, int E,
                            const float* __restrict__ W1, const float* __restrict__ W2,
                            const float* __restrict__ W3, ushort* __restrict__ Wf,
                            int xbB, int cntB) {
  int b = blockIdx.x;
  int tid = threadIdx.x;
  if (b < xbB) {
    int i = b * 256 + tid;
    if (i < total4) {
      float4 v = ((const float4*)x)[i];
      uint2 o;
      o.x = packbf2(v.x, v.y);
      o.y = packbf2(v.z, v.w);
      ((uint2*)xb)[i] = o;
    }
  } else if (b < xbB + cntB) {
    int e = (b - xbB) * 256 + tid;
    if (e < E) atomicAdd(&cnt[dst[e]], 1);
  } else {
    int idx = (b - xbB - cntB) * 256 + tid;  // 0..98303
    int which = idx >> 15;
    int id = idx & 32767;
    const float* W = (which == 0) ? W1 : ((which == 1) ? W2 : W3);
    int j = id & 7;
    int l = (id >> 3) & 63;
    int f = id >> 9;
    int p = f & 1, kc = (f >> 1) & 3, ct = f >> 3;
    int k = kc * 32 + (l >> 4) * 8 + j;
    int col = ct * 16 + (l & 15);
    float w = W[k * D + col];
    ushort hi = bf16rne(w);
    ushort outv = hi;
    if (p) {
      float hf = __uint_as_float((uint32)hi << 16);
      outv = bf16rne(w - hf);
    }
    Wf[idx] = outv;
  }
}

// ---------------- CSR build ----------------

__global__ void scan1_kernel(const int* __restrict__ cnt, int* __restrict__ off,
                             int* __restrict__ bsum, float* __restrict__ dis, int n) {
  __shared__ int tsum[SB];
  int tid = threadIdx.x;
  int base = blockIdx.x * SCHUNK;
  int v[SI];
  int s = 0;
#pragma unroll
  for (int i = 0; i < SI; i++) {
    int idx = base + tid * SI + i;
    v[i] = (idx < n) ? cnt[idx] : 0;
    s += v[i];
  }
  tsum[tid] = s;
  __syncthreads();
  for (int o = 1; o < SB; o <<= 1) {
    int t = (tid >= o) ? tsum[tid - o] : 0;
    __syncthreads();
    tsum[tid] += t;
    __syncthreads();
  }
  int run = tsum[tid] - s;
#pragma unroll
  for (int i = 0; i < SI; i++) {
    int idx = base + tid * SI + i;
    if (idx < n) {
      off[idx] = run;
      dis[idx] = rsqrtf((float)(v[i] + 1));
    }
    run += v[i];
  }
  if (tid == SB - 1) bsum[blockIdx.x] = tsum[tid];
}

// scan3: adds cross-chunk base (computed in-kernel from bsum; nb <= 64)
__global__ void scan3_kernel(int* __restrict__ off, const int* __restrict__ bsum,
                             int n, int total) {
  __shared__ int cbase;
  int b = blockIdx.x;
  int tid = threadIdx.x;
  int c = (b * 256) / SCHUNK;  // whole block lies in one chunk
  if (tid < 64) {
    int v = (tid < c) ? bsum[tid] : 0;
#pragma unroll
    for (int o = 32; o; o >>= 1) v += __shfl_down(v, o);
    if (tid == 0) cbase = v;
  }
  __syncthreads();
  int i = b * 256 + tid;
  if (i < n) off[i] += cbase;
  if (i == 0) off[n] = total;
}

// fill: uses cnt as countdown cursor (destroys it -> cnt ends all-zero)
__global__ void fill_kernel(const int* __restrict__ src, const int* __restrict__ dst,
                            const int* __restrict__ off, int* __restrict__ cnt,
                            uint2* __restrict__ epack, const float* __restrict__ dis, int E) {
  int e = blockIdx.x * blockDim.x + threadIdx.x;
  if (e >= E) return;
  int s = src[e], d = dst[e];
  int slot = atomicSub(&cnt[d], 1) - 1;
  int p = off[d] + slot;
  uint2 v;
  v.x = (uint32)s;
  v.y = __float_as_uint(dis[s] * dis[d]);
  epack[p] = v;
}

// ------- fused layer: out = [relu](Agg(t) @ W + bias) ----------------------
// gather-first; barrier-free per-wave slices; dual edge pipeline per group.

template <int FINAL>
__global__ __launch_bounds__(256) void fused_kernel(const ushort* __restrict__ t,
                                                    const uint2* __restrict__ epack,
                                                    const int* __restrict__ off,
                                                    const float* __restrict__ dis,
                                                    const ushort* __restrict__ Wf,
                                                    const float* __restrict__ bias,
                                                    void* __restrict__ outp, int N) {
  __shared__ char lds[16384];
  int tid = threadIdx.x;
  int row0 = blockIdx.x * 64;
  int lane = tid & 63, wv = tid >> 6;
  int q = lane & 15, g = lane >> 4;
  int qb = q * 16;
  const char* tb = (const char*)t;

#pragma unroll 1
  for (int pair = 0; pair < 2; pair++) {
    int rA = wv * 16 + pair * 8 + g;
    int rB = rA + 4;
    int nodeA = row0 + rA, nodeB = row0 + rB;
    bool vA = nodeA < N, vB = nodeB < N;
    int nA = vA ? nodeA : 0, nB = vB ? nodeB : 0;

    float aA[8], aB[8];
#pragma unroll
    for (int i = 0; i < 8; i++) { aA[i] = 0.f; aB[i] = 0.f; }

    // independent self-loop loads first
    uint4 hsA = *(const uint4*)(tb + (((uint32)nA << 8) + qb));
    uint4 hsB = *(const uint4*)(tb + (((uint32)nB << 8) + qb));
    int j0A = vA ? off[nodeA] : 0, j1A = vA ? off[nodeA + 1] : 0;
    int j0B = vB ? off[nodeB] : 0, j1B = vB ? off[nodeB + 1] : 0;
    float dA = vA ? dis[nodeA] : 0.f, dB = vB ? dis[nodeB] : 0.f;
    float swA = dA * dA, swB = dB * dB;

    auto ldA = [&](int idx) -> uint2 {
      if (idx < j1A) return epack[idx];
      uint2 z; z.x = (uint32)nA; z.y = 0u; return z;
    };
    auto ldB = [&](int idx) -> uint2 {
      if (idx < j1B) return epack[idx];
      uint2 z; z.x = (uint32)nB; z.y = 0u; return z;
    };

    int jA = j0A, jB = j0B;
    uint2 eA0 = ldA(jA), eA1 = ldA(jA + 1), eA2 = ldA(jA + 2), eA3 = ldA(jA + 3);
    uint2 eB0 = ldB(jB), eB1 = ldB(jB + 1), eB2 = ldB(jB + 2), eB3 = ldB(jB + 3);
    while (jA < j1A || jB < j1B) {
      uint4 hA0 = *(const uint4*)(tb + ((eA0.x << 8) + qb));
      uint4 hA1 = *(const uint4*)(tb + ((eA1.x << 8) + qb));
      uint4 hA2 = *(const uint4*)(tb + ((eA2.x << 8) + qb));
      uint4 hA3 = *(const uint4*)(tb + ((eA3.x << 8) + qb));
      uint4 hB0 = *(const uint4*)(tb + ((eB0.x << 8) + qb));
      uint4 hB1 = *(const uint4*)(tb + ((eB1.x << 8) + qb));
      uint4 hB2 = *(const uint4*)(tb + ((eB2.x << 8) + qb));
      uint4 hB3 = *(const uint4*)(tb + ((eB3.x << 8) + qb));
      float wA0 = __uint_as_float(eA0.y), wA1 = __uint_as_float(eA1.y);
      float wA2 = __uint_as_float(eA2.y), wA3 = __uint_as_float(eA3.y);
      float wB0 = __uint_as_float(eB0.y), wB1 = __uint_as_float(eB1.y);
      float wB2 = __uint_as_float(eB2.y), wB3 = __uint_as_float(eB3.y);
      jA += 4; jB += 4;
      eA0 = ldA(jA); eA1 = ldA(jA + 1); eA2 = ldA(jA + 2); eA3 = ldA(jA + 3);
      eB0 = ldB(jB); eB1 = ldB(jB + 1); eB2 = ldB(jB + 2); eB3 = ldB(jB + 3);
      acc8(aA, wA0, hA0); acc8(aA, wA1, hA1); acc8(aA, wA2, hA2); acc8(aA, wA3, hA3);
      acc8(aB, wB0, hB0); acc8(aB, wB1, hB1); acc8(aB, wB2, hB2); acc8(aB, wB3, hB3);
    }
    acc8(aA, swA, hsA);
    acc8(aB, swB, hsB);

    uint4 pA, pB;
    pA.x = packbf2(aA[0], aA[1]); pA.y = packbf2(aA[2], aA[3]);
    pA.z = packbf2(aA[4], aA[5]); pA.w = packbf2(aA[6], aA[7]);
    pB.x = packbf2(aB[0], aB[1]); pB.y = packbf2(aB[2], aB[3]);
    pB.z = packbf2(aB[4], aB[5]); pB.w = packbf2(aB[6], aB[7]);
    int boffA = (rA * 256 + qb) ^ ((rA & 7) << 4);
    int boffB = (rB * 256 + qb) ^ ((rB & 7) << 4);
    *(uint4*)(lds + boffA) = pA;
    *(uint4*)(lds + boffB) = pB;
  }
  lds_fence();  // wave's own LDS writes visible to all its lanes

  // ---- MFMA: z(16x128, own slice) @ W(128x128), W as hi+lo bf16 ----
  int lr = lane & 15, lg = lane >> 4;
  int m0 = wv * 16;

  bf16x8 af[4];
#pragma unroll
  for (int kc = 0; kc < 4; kc++) {
    int row = m0 + lr;
    int boff = (row * 256 + kc * 64 + lg * 16) ^ ((row & 7) << 4);
    af[kc] = *(bf16x8*)(lds + boff);
  }

  float bcol[8];
#pragma unroll
  for (int ct = 0; ct < 8; ct++) bcol[ct] = bias[ct * 16 + lr];

  f32x4 acc[8];
#pragma unroll
  for (int ct = 0; ct < 8; ct++) acc[ct] = (f32x4){0.f, 0.f, 0.f, 0.f};

#pragma unroll 1
  for (int ct = 0; ct < 8; ct++) {
    bf16x8 bf_[4][2];
#pragma unroll
    for (int kc = 0; kc < 4; kc++)
#pragma unroll
      for (int p = 0; p < 2; p++)
        bf_[kc][p] = *(const bf16x8*)&Wf[(size_t)((((ct * 4 + kc) * 2 + p) * 64 + lane) * 8)];
#pragma unroll
    for (int kc = 0; kc < 4; kc++) {
      acc[ct] = __builtin_amdgcn_mfma_f32_16x16x32_bf16(af[kc], bf_[kc][0], acc[ct], 0, 0, 0);
      acc[ct] = __builtin_amdgcn_mfma_f32_16x16x32_bf16(af[kc], bf_[kc][1], acc[ct], 0, 0, 0);
    }
  }
  lds_fence();  // af reads complete before slice is overwritten

  if (FINAL) {
    float* out = (float*)outp;
#pragma unroll
    for (int p = 0; p < 2; p++) {
#pragma unroll
      for (int c4 = 0; c4 < 4; c4++) {
        int ct = p * 4 + c4;
#pragma unroll
        for (int r = 0; r < 4; r++) {
          int row = m0 + lg * 4 + r;
          int colb = c4 * 16 + lr;
          float v = acc[ct][r] + bcol[ct];
          int boff = (row * 256 + colb * 4) ^ ((row & 7) << 4);
          *(float*)(lds + boff) = v;
        }
      }
      lds_fence();
#pragma unroll
      for (int i = 0; i < 4; i++) {
        int f = wv * 4096 + i * 1024 + lane * 16;
        int row = f >> 8;
        int boff = f ^ ((row & 7) << 4);
        if (row0 + row < N) {
          uint4 v = *(uint4*)(lds + boff);
          *(uint4*)((char*)out + (size_t)(row0 + row) * 512 + p * 256 + (f & 255)) = v;
        }
      }
      lds_fence();  // readback done before next pass overwrites
    }
  } else {
#pragma unroll
    for (int ct = 0; ct < 8; ct++)
#pragma unroll
      for (int r = 0; r < 4; r++) {
        int row = m0 + lg * 4 + r;
        int col = ct * 16 + lr;
        float v = fmaxf(acc[ct][r] + bcol[ct], 0.f);
        int boff = (row * 256 + col * 2) ^ ((row & 7) << 4);
        *(ushort*)(lds + boff) = bf16rne(v);
      }
    lds_fence();
    ushort* outb = (ushort*)outp;
#pragma unroll
    for (int i = 0; i < 4; i++) {
      int f = wv * 4096 + i * 1024 + lane * 16;
      int row = f >> 8;
      int boff = f ^ ((row & 7) << 4);
      if (row0 + row < N) {
        uint4 v = *(uint4*)(lds + boff);
        *(uint4*)((char*)outb + (size_t)(row0 + row) * 256 + (f & 255)) = v;
      }
    }
  }
}

// ---------------- launch ----------------

extern "C" void kernel_launch(void* const* d_in, const int* in_sizes, int n_in,
                              void* d_out, int out_size, void* d_ws, size_t ws_size,
                              hipStream_t stream) {
  const float* x  = (const float*)d_in[0];
  const int*   ei = (const int*)d_in[1];
  const float* W1 = (const float*)d_in[2];
  const float* b1 = (const float*)d_in[3];
  const float* W2 = (const float*)d_in[4];
  const float* b2 = (const float*)d_in[5];
  const float* W3 = (const float*)d_in[6];
  const float* b3 = (const float*)d_in[7];
  int N = in_sizes[0] / D;
  int E = in_sizes[1] / 2;
  const int* srcp = ei;
  const int* dstp = ei + E;

  char* wp = (char*)d_ws;
  auto carve = [&](size_t bytes) {
    void* p = (void*)wp;
    wp += (bytes + 255) & ~(size_t)255;
    return p;
  };
  int*    cnt   = (int*)carve((size_t)N * 4);
  int*    off   = (int*)carve((size_t)(N + 1) * 4);
  int*    bsum  = (int*)carve(256 * 4);
  float*  dis   = (float*)carve((size_t)N * 4);
  uint2*  epack = (uint2*)carve((size_t)E * 8);
  ushort* xb    = (ushort*)carve((size_t)N * D * 2);
  ushort* t1    = (ushort*)carve((size_t)N * D * 2);
  ushort* t2    = (ushort*)carve((size_t)N * D * 2);
  ushort* wfall = (ushort*)carve((size_t)3 * 32768 * 2);
  ushort* wf1 = wfall, *wf2 = wfall + 32768, *wf3 = wfall + 65536;

  hipMemsetAsync(cnt, 0, (size_t)N * 4, stream);

  const int tb = 256;
  int total4 = N * D / 4;
  int xbB = (total4 + 255) / 256;
  int cntB = (E + 255) / 256;
  prep_kernel<<<xbB + cntB + 384, 256, 0, stream>>>(x, xb, total4, dstp, cnt, E,
                                                    W1, W2, W3, wfall, xbB, cntB);
  int nb = (N + SCHUNK - 1) / SCHUNK;
  scan1_kernel<<<nb, SB, 0, stream>>>(cnt, off, bsum, dis, N);
  scan3_kernel<<<(N + tb - 1) / tb, tb, 0, stream>>>(off, bsum, N, E);
  fill_kernel<<<(E + tb - 1) / tb, tb, 0, stream>>>(srcp, dstp, off, cnt, epack, dis, E);

  int fb = (N + 63) / 64;
  fused_kernel<0><<<fb, 256, 0, stream>>>(xb, epack, off, dis, wf1, b1, t1, N);
  fused_kernel<0><<<fb, 256, 0, stream>>>(t1, epack, off, dis, wf2, b2, t2, N);
  fused_kernel<1><<<fb, 256, 0, stream>>>(t2, epack, off, dis, wf3, b3, d_out, N);
}

// Round 8
// 241.406 us; speedup vs baseline: 1.0420x; 1.0420x over previous
//
#include <hip/hip_runtime.h>

#define D 128
#define SB 256
#define SI 8
#define SCHUNK (SB * SI)

typedef __attribute__((ext_vector_type(8))) short bf16x8;
typedef __attribute__((ext_vector_type(4))) float f32x4;
typedef unsigned int uint32;
typedef unsigned short ushort;

__device__ __forceinline__ ushort bf16rne(float f) {
  uint32 u = __float_as_uint(f);
  uint32 r = u + 0x7FFFu + ((u >> 16) & 1u);
  return (ushort)(r >> 16);
}
__device__ __forceinline__ float bf2f_lo(uint32 h) { return __uint_as_float(h << 16); }
__device__ __forceinline__ float bf2f_hi(uint32 h) { return __uint_as_float(h & 0xFFFF0000u); }
__device__ __forceinline__ uint32 packbf2(float x, float y) {
  return (uint32)bf16rne(x) | ((uint32)bf16rne(y) << 16);
}
__device__ __forceinline__ void acc8(float* a, float w, uint4 h) {
  a[0] += w * bf2f_lo(h.x); a[1] += w * bf2f_hi(h.x);
  a[2] += w * bf2f_lo(h.y); a[3] += w * bf2f_hi(h.y);
  a[4] += w * bf2f_lo(h.z); a[5] += w * bf2f_hi(h.z);
  a[6] += w * bf2f_lo(h.w); a[7] += w * bf2f_hi(h.w);
}

// ---------------- prep: xb convert + degree count + W-conv, one launch -----

__global__ void prep_kernel(const float* __restrict__ x, ushort* __restrict__ xb, int total4,
                            const int* __restrict__ dst, int* __restrict__ cnt, int E,
                            const float* __restrict__ W1, const float* __restrict__ W2,
                            const float* __restrict__ W3, ushort* __restrict__ Wf,
                            int xbB, int cntB) {
  int b = blockIdx.x;
  int tid = threadIdx.x;
  if (b < xbB) {
    int i = b * 256 + tid;
    if (i < total4) {
      float4 v = ((const float4*)x)[i];
      uint2 o;
      o.x = packbf2(v.x, v.y);
      o.y = packbf2(v.z, v.w);
      ((uint2*)xb)[i] = o;
    }
  } else if (b < xbB + cntB) {
    int e = (b - xbB) * 256 + tid;
    if (e < E) atomicAdd(&cnt[dst[e]], 1);
  } else {
    int idx = (b - xbB - cntB) * 256 + tid;  // 0..98303
    int which = idx >> 15;
    int id = idx & 32767;
    const float* W = (which == 0) ? W1 : ((which == 1) ? W2 : W3);
    int j = id & 7;
    int l = (id >> 3) & 63;
    int f = id >> 9;
    int p = f & 1, kc = (f >> 1) & 3, ct = f >> 3;
    int k = kc * 32 + (l >> 4) * 8 + j;
    int col = ct * 16 + (l & 15);
    float w = W[k * D + col];
    ushort hi = bf16rne(w);
    ushort outv = hi;
    if (p) {
      float hf = __uint_as_float((uint32)hi << 16);
      outv = bf16rne(w - hf);
    }
    Wf[idx] = outv;
  }
}

// ---------------- CSR build ----------------

__global__ void scan1_kernel(const int* __restrict__ cnt, int* __restrict__ off,
                             int* __restrict__ bsum, float* __restrict__ dis, int n) {
  __shared__ int tsum[SB];
  int tid = threadIdx.x;
  int base = blockIdx.x * SCHUNK;
  int v[SI];
  int s = 0;
#pragma unroll
  for (int i = 0; i < SI; i++) {
    int idx = base + tid * SI + i;
    v[i] = (idx < n) ? cnt[idx] : 0;
    s += v[i];
  }
  tsum[tid] = s;
  __syncthreads();
  for (int o = 1; o < SB; o <<= 1) {
    int t = (tid >= o) ? tsum[tid - o] : 0;
    __syncthreads();
    tsum[tid] += t;
    __syncthreads();
  }
  int run = tsum[tid] - s;
#pragma unroll
  for (int i = 0; i < SI; i++) {
    int idx = base + tid * SI + i;
    if (idx < n) {
      off[idx] = run;
      dis[idx] = rsqrtf((float)(v[i] + 1));
    }
    run += v[i];
  }
  if (tid == SB - 1) bsum[blockIdx.x] = tsum[tid];
}

// scan3: adds cross-chunk base (computed in-kernel from bsum; nb <= 64)
__global__ void scan3_kernel(int* __restrict__ off, const int* __restrict__ bsum,
                             int n, int total) {
  __shared__ int cbase;
  int b = blockIdx.x;
  int tid = threadIdx.x;
  int c = (b * 256) / SCHUNK;  // whole block lies in one chunk
  if (tid < 64) {
    int v = (tid < c) ? bsum[tid] : 0;
#pragma unroll
    for (int o = 32; o; o >>= 1) v += __shfl_down(v, o);
    if (tid == 0) cbase = v;
  }
  __syncthreads();
  int i = b * 256 + tid;
  if (i < n) off[i] += cbase;
  if (i == 0) off[n] = total;
}

// fill: uses cnt as countdown cursor (destroys it -> cnt ends all-zero)
__global__ void fill_kernel(const int* __restrict__ src, const int* __restrict__ dst,
                            const int* __restrict__ off, int* __restrict__ cnt,
                            uint2* __restrict__ epack, const float* __restrict__ dis, int E) {
  int e = blockIdx.x * blockDim.x + threadIdx.x;
  if (e >= E) return;
  int s = src[e], d = dst[e];
  int slot = atomicSub(&cnt[d], 1) - 1;
  int p = off[d] + slot;
  uint2 v;
  v.x = (uint32)s;
  v.y = __float_as_uint(dis[s] * dis[d]);
  epack[p] = v;
}

// ------- fused layer: out = [relu](Agg(t) @ W + bias) ----------------------
// gather-first (Agg commutes with @W). M=64 rows/block, 16KB LDS.
// 8-deep edge pipeline per 16-lane group: deg<=8 rows need ONE mem round-trip.

template <int FINAL>
__global__ __launch_bounds__(256, 4) void fused_kernel(const ushort* __restrict__ t,
                                                       const uint2* __restrict__ epack,
                                                       const int* __restrict__ off,
                                                       const float* __restrict__ dis,
                                                       const ushort* __restrict__ Wf,
                                                       const float* __restrict__ bias,
                                                       void* __restrict__ outp, int N) {
  __shared__ char lds[16384];
  int tid = threadIdx.x;
  int row0 = blockIdx.x * 64;
  int lane = tid & 63, wv = tid >> 6;
  int q = lane & 15, g = lane >> 4;
  int qb = q * 16;
  const char* tb = (const char*)t;

#pragma unroll 1
  for (int n4 = 0; n4 < 4; n4++) {
    int r = wv * 16 + n4 * 4 + g;
    int node = row0 + r;
    float a[8];
#pragma unroll
    for (int i = 0; i < 8; i++) a[i] = 0.f;

    if (node < N) {
      // self-loop load first (independent, also serves as L1-warm dummy row)
      uint32 soff = ((uint32)node << 8) + qb;
      uint4 hs = *(const uint4*)(tb + soff);
      int j0 = off[node], j1 = off[node + 1];
      float dsv = dis[node];
      float sw = dsv * dsv;

      auto ldE = [&](int idx) -> uint2 {
        if (idx < j1) return epack[idx];
        uint2 z; z.x = (uint32)node; z.y = 0u; return z;  // self row, weight 0
      };
      int j = j0;
      uint2 e0 = ldE(j), e1 = ldE(j + 1), e2 = ldE(j + 2), e3 = ldE(j + 3);
      uint2 e4 = ldE(j + 4), e5 = ldE(j + 5), e6 = ldE(j + 6), e7 = ldE(j + 7);
      while (j < j1) {
        uint4 h0 = *(const uint4*)(tb + ((e0.x << 8) + qb));
        uint4 h1 = *(const uint4*)(tb + ((e1.x << 8) + qb));
        uint4 h2 = *(const uint4*)(tb + ((e2.x << 8) + qb));
        uint4 h3 = *(const uint4*)(tb + ((e3.x << 8) + qb));
        uint4 h4 = *(const uint4*)(tb + ((e4.x << 8) + qb));
        uint4 h5 = *(const uint4*)(tb + ((e5.x << 8) + qb));
        uint4 h6 = *(const uint4*)(tb + ((e6.x << 8) + qb));
        uint4 h7 = *(const uint4*)(tb + ((e7.x << 8) + qb));
        float w0 = __uint_as_float(e0.y), w1 = __uint_as_float(e1.y);
        float w2 = __uint_as_float(e2.y), w3 = __uint_as_float(e3.y);
        float w4 = __uint_as_float(e4.y), w5 = __uint_as_float(e5.y);
        float w6 = __uint_as_float(e6.y), w7 = __uint_as_float(e7.y);
        int jn = j + 8;
        e0 = ldE(jn); e1 = ldE(jn + 1); e2 = ldE(jn + 2); e3 = ldE(jn + 3);
        e4 = ldE(jn + 4); e5 = ldE(jn + 5); e6 = ldE(jn + 6); e7 = ldE(jn + 7);
        acc8(a, w0, h0); acc8(a, w1, h1); acc8(a, w2, h2); acc8(a, w3, h3);
        acc8(a, w4, h4); acc8(a, w5, h5); acc8(a, w6, h6); acc8(a, w7, h7);
        j = jn;
      }
      acc8(a, sw, hs);
    }
    uint4 pv;
    pv.x = packbf2(a[0], a[1]);
    pv.y = packbf2(a[2], a[3]);
    pv.z = packbf2(a[4], a[5]);
    pv.w = packbf2(a[6], a[7]);
    int boff = (r * 256 + qb) ^ ((r & 7) << 4);
    *(uint4*)(lds + boff) = pv;
  }
  __syncthreads();

  // ---- MFMA: z(64x128) @ W(128x128), W as hi+lo bf16 ----
  int lr = lane & 15, lg = lane >> 4;
  int m0 = wv * 16;

  bf16x8 af[4];
#pragma unroll
  for (int kc = 0; kc < 4; kc++) {
    int row = m0 + lr;
    int boff = (row * 256 + kc * 64 + lg * 16) ^ ((row & 7) << 4);
    af[kc] = *(bf16x8*)(lds + boff);
  }

  float bcol[8];
#pragma unroll
  for (int ct = 0; ct < 8; ct++) bcol[ct] = bias[ct * 16 + lr];

  f32x4 acc[8];
#pragma unroll
  for (int ct = 0; ct < 8; ct++) acc[ct] = (f32x4){0.f, 0.f, 0.f, 0.f};

#pragma unroll 1
  for (int ct = 0; ct < 8; ct++) {
    bf16x8 bf_[4][2];
#pragma unroll
    for (int kc = 0; kc < 4; kc++)
#pragma unroll
      for (int p = 0; p < 2; p++)
        bf_[kc][p] = *(const bf16x8*)&Wf[(size_t)((((ct * 4 + kc) * 2 + p) * 64 + lane) * 8)];
#pragma unroll
    for (int kc = 0; kc < 4; kc++) {
      acc[ct] = __builtin_amdgcn_mfma_f32_16x16x32_bf16(af[kc], bf_[kc][0], acc[ct], 0, 0, 0);
      acc[ct] = __builtin_amdgcn_mfma_f32_16x16x32_bf16(af[kc], bf_[kc][1], acc[ct], 0, 0, 0);
    }
  }
  __syncthreads();

  if (FINAL) {
    // fp32 epilogue: two 64-column passes through 16KB LDS
    float* out = (float*)outp;
#pragma unroll
    for (int p = 0; p < 2; p++) {
#pragma unroll
      for (int c4 = 0; c4 < 4; c4++) {
        int ct = p * 4 + c4;
#pragma unroll
        for (int r = 0; r < 4; r++) {
          int row = m0 + lg * 4 + r;
          int colb = c4 * 16 + lr;  // 0..63 within pass
          float v = acc[ct][r] + bcol[ct];
          int boff = (row * 256 + colb * 4) ^ ((row & 7) << 4);
          *(float*)(lds + boff) = v;
        }
      }
      __syncthreads();
#pragma unroll
      for (int i = 0; i < 4; i++) {
        int f = i * 4096 + tid * 16;
        int row = f >> 8;
        int boff = f ^ ((row & 7) << 4);
        if (row0 + row < N) {
          uint4 v = *(uint4*)(lds + boff);
          *(uint4*)((char*)out + (size_t)(row0 + row) * 512 + p * 256 + (f & 255)) = v;
        }
      }
      if (p == 0) __syncthreads();
    }
  } else {
    // bf16 epilogue: bias + relu through 16KB LDS
#pragma unroll
    for (int ct = 0; ct < 8; ct++)
#pragma unroll
      for (int r = 0; r < 4; r++) {
        int row = m0 + lg * 4 + r;
        int col = ct * 16 + lr;
        float v = fmaxf(acc[ct][r] + bcol[ct], 0.f);
        int boff = (row * 256 + col * 2) ^ ((row & 7) << 4);
        *(ushort*)(lds + boff) = bf16rne(v);
      }
    __syncthreads();
    ushort* outb = (ushort*)outp;
#pragma unroll
    for (int i = 0; i < 4; i++) {
      int f = i * 4096 + tid * 16;
      int row = f >> 8;
      int boff = f ^ ((row & 7) << 4);
      if (row0 + row < N) {
        uint4 v = *(uint4*)(lds + boff);
        *(uint4*)((char*)outb + (size_t)(row0 + row) * 256 + (f & 255)) = v;
      }
    }
  }
}

// ---------------- launch ----------------

extern "C" void kernel_launch(void* const* d_in, const int* in_sizes, int n_in,
                              void* d_out, int out_size, void* d_ws, size_t ws_size,
                              hipStream_t stream) {
  const float* x  = (const float*)d_in[0];
  const int*   ei = (const int*)d_in[1];
  const float* W1 = (const float*)d_in[2];
  const float* b1 = (const float*)d_in[3];
  const float* W2 = (const float*)d_in[4];
  const float* b2 = (const float*)d_in[5];
  const float* W3 = (const float*)d_in[6];
  const float* b3 = (const float*)d_in[7];
  int N = in_sizes[0] / D;
  int E = in_sizes[1] / 2;
  const int* srcp = ei;
  const int* dstp = ei + E;

  char* wp = (char*)d_ws;
  auto carve = [&](size_t bytes) {
    void* p = (void*)wp;
    wp += (bytes + 255) & ~(size_t)255;
    return p;
  };
  int*    cnt   = (int*)carve((size_t)N * 4);
  int*    off   = (int*)carve((size_t)(N + 1) * 4);
  int*    bsum  = (int*)carve(256 * 4);
  float*  dis   = (float*)carve((size_t)N * 4);
  uint2*  epack = (uint2*)carve((size_t)E * 8);
  ushort* xb    = (ushort*)carve((size_t)N * D * 2);
  ushort* t1    = (ushort*)carve((size_t)N * D * 2);
  ushort* t2    = (ushort*)carve((size_t)N * D * 2);
  ushort* wfall = (ushort*)carve((size_t)3 * 32768 * 2);
  ushort* wf1 = wfall, *wf2 = wfall + 32768, *wf3 = wfall + 65536;

  hipMemsetAsync(cnt, 0, (size_t)N * 4, stream);

  const int tb = 256;
  int total4 = N * D / 4;
  int xbB = (total4 + 255) / 256;
  int cntB = (E + 255) / 256;
  prep_kernel<<<xbB + cntB + 384, 256, 0, stream>>>(x, xb, total4, dstp, cnt, E,
                                                    W1, W2, W3, wfall, xbB, cntB);
  int nb = (N + SCHUNK - 1) / SCHUNK;
  scan1_kernel<<<nb, SB, 0, stream>>>(cnt, off, bsum, dis, N);
  scan3_kernel<<<(N + tb - 1) / tb, tb, 0, stream>>>(off, bsum, N, E);
  fill_kernel<<<(E + tb - 1) / tb, tb, 0, stream>>>(srcp, dstp, off, cnt, epack, dis, E);

  int fb = (N + 63) / 64;
  fused_kernel<0><<<fb, 256, 0, stream>>>(xb, epack, off, dis, wf1, b1, t1, N);
  fused_kernel<0><<<fb, 256, 0, stream>>>(t1, epack, off, dis, wf2, b2, t2, N);
  fused_kernel<1><<<fb, 256, 0, stream>>>(t2, epack, off, dis, wf3, b3, d_out, N);
}